// Round 1
// 518.337 us; speedup vs baseline: 1.0182x; 1.0182x over previous
//
#include <hip/hip_runtime.h>

// DecoderStack: B=4,T=1024,D=1024,H=16,DK=DV=64,FF=4096
// Softmax over QUERY axis: l_s = sum_t exp(S) via store-free l-pass (EPI=4),
// 1/l_s folded into V (vscale), then fused attn_pv_k recomputes E per tile in
// LDS and multiplies by V — E never touches HBM.
// sub_norm(o) = o - mean - std (ddof=1).
// This round: big GEMMs (QKV1/KV2/FFN-in/FFN-out) moved to gemm8_k —
// 256x256 tile, 8 waves, 4-phase-per-K-tile schedule with counted vmcnt(10)
// (never drains in main loop), raw s_barriers, setprio around MFMA clusters.

typedef unsigned short u16;
typedef __bf16 bf16x8 __attribute__((ext_vector_type(8)));
typedef float f32x4 __attribute__((ext_vector_type(4)));

__device__ __forceinline__ u16 f2bf(float f) {
    unsigned int u = __float_as_uint(f);
    u += 0x7fffu + ((u >> 16) & 1u);   // RNE; inputs are finite
    return (u16)(u >> 16);
}
__device__ __forceinline__ float bf2f(u16 b) {
    return __uint_as_float(((unsigned int)b) << 16);
}

typedef __attribute__((address_space(1))) const void* as1cv;
typedef __attribute__((address_space(3))) void* as3v;
__device__ __forceinline__ void gl_lds16(const void* g, void* l) {
    __builtin_amdgcn_global_load_lds((as1cv)g, (as3v)l, 16, 0, 0);
}

// ---------------- converts / packs ----------------

__global__ __launch_bounds__(256) void convert_f2b_k(const float* __restrict__ in, u16* __restrict__ out) {
    long i = (long)blockIdx.x * 256 + threadIdx.x;
    float4 v = reinterpret_cast<const float4*>(in)[i];
    ushort4 o;
    o.x = f2bf(v.x); o.y = f2bf(v.y); o.z = f2bf(v.z); o.w = f2bf(v.w);
    reinterpret_cast<ushort4*>(out)[i] = o;
}

// out[p][r][q] = in[p][q][r] (fp32->bf16), LDS-tiled. grid (R/64, Q/64, P)
__global__ __launch_bounds__(256) void pack_perm_t(const float* __restrict__ in, u16* __restrict__ out,
                                                   int Q, int R) {
    __shared__ float tile[64][65];
    int p = blockIdx.z;
    int r0 = blockIdx.x * 64, q0 = blockIdx.y * 64;
    int tx = threadIdx.x & 63, ty = threadIdx.x >> 6;
    const float* inp = in + ((long)p * Q + q0) * R + r0;
    #pragma unroll
    for (int i = 0; i < 64; i += 4)
        tile[ty + i][tx] = inp[(long)(ty + i) * R + tx];
    __syncthreads();
    u16* outp = out + ((long)p * R + r0) * Q + q0;
    #pragma unroll
    for (int i = 0; i < 64; i += 4)
        outp[(long)(ty + i) * Q + tx] = f2bf(tile[tx][ty + i]);
}

// 64x64 tiled bf16 transpose: out[c][r] = in[r][c], batched over z
__global__ __launch_bounds__(256) void transpose_k(const u16* __restrict__ in, long ld_in, long z_in,
                                                   u16* __restrict__ out, long ld_out, long z_out) {
    __shared__ u16 tile[64][66];
    const u16* inz = in + (long)blockIdx.z * z_in;
    u16* outz = out + (long)blockIdx.z * z_out;
    int r0 = blockIdx.y * 64;
    int c0 = blockIdx.x * 64;
    int tx = threadIdx.x & 63, ty = threadIdx.x >> 6;
    #pragma unroll
    for (int i = 0; i < 64; i += 4)
        tile[ty + i][tx] = inz[(long)(r0 + ty + i) * ld_in + c0 + tx];
    __syncthreads();
    #pragma unroll
    for (int i = 0; i < 64; i += 4)
        outz[(long)(c0 + ty + i) * ld_out + r0 + tx] = tile[tx][ty + i];
}

// ---------------- legacy GEMM (kept for l-pass EPI=4 and small Wo split-K) ----------------
template<int BM, int BN, int BK, int WM, int WN, int OUT_BF16, int EPI, int SWZ, int KS>
__global__ __launch_bounds__(256) void gemm_k(
    const u16* __restrict__ A, long lda, long a_zin, long a_zout,
    const u16* __restrict__ B, long ldb, long b_zin, long b_zout,
    void* __restrict__ Cv, long ldc, long c_zin, long c_zout,
    int zin, int K, float alpha, const float* __restrict__ bias,
    float* __restrict__ csum)
{
    static_assert(BK == 64, "staging assumes BK=64");
    constexpr int WTM = BM / WM;
    constexpr int WTN = BN / WN;
    constexpr int TM = WTM / 16;
    constexpr int TN = WTN / 16;
    __shared__ __align__(16) u16 smem[(BM + BN) * BK];
    u16* As = smem;
    u16* Bs = smem + BM * BK;

    int bx, by, z;
    if (SWZ == 4) {
        int L = blockIdx.x;
        if (KS > 1) { z = L >> 9; L &= 511; } else { z = 0; }
        by = (L & 7) * 4 + ((L >> 3) & 3);
        bx = L >> 5;
    } else {
        bx = blockIdx.x; by = blockIdx.y; z = blockIdx.z;
    }
    int zi = z % zin, zo = z / zin;
    A += (long)zi * a_zin + (long)zo * a_zout;
    B += (long)zi * b_zin + (long)zo * b_zout;
    long coff = (long)zi * c_zin + (long)zo * c_zout;

    int tid = threadIdx.x;
    int lane = tid & 63;
    int wave = tid >> 6;
    int wm = wave / WN, wn = wave % WN;
    long bm0 = (long)by * BM, bn0 = (long)bx * BN;

    f32x4 acc[TM][TN];
    #pragma unroll
    for (int i = 0; i < TM; ++i)
        #pragma unroll
        for (int j = 0; j < TN; ++j) {
            acc[i][j][0] = 0.f; acc[i][j][1] = 0.f;
            acc[i][j][2] = 0.f; acc[i][j][3] = 0.f;
        }

    int r16 = lane & 15;
    int quad = lane >> 4;
    int l8 = lane >> 3;                    // stripe row
    int gsw = ((lane & 7) ^ l8) * 8;       // swizzled global col (elements)

    constexpr int ASTR = BM / 8;
    constexpr int BSTR = BN / 8;

    for (int k0 = 0; k0 < K; k0 += BK) {
        #pragma unroll
        for (int s = wave; s < ASTR; s += 4)
            gl_lds16(&A[(bm0 + s * 8 + l8) * lda + k0 + gsw], &As[s * 512]);
        #pragma unroll
        for (int s = wave; s < BSTR; s += 4)
            gl_lds16(&B[(bn0 + s * 8 + l8) * ldb + k0 + gsw], &Bs[s * 512]);
        __syncthreads();
        #pragma unroll
        for (int kk = 0; kk < BK; kk += 32) {
            int cb = (kk >> 3) + quad;
            bf16x8 av[TM], bv[TN];
            #pragma unroll
            for (int i = 0; i < TM; ++i) {
                int r = wm * WTM + i * 16 + r16;
                av[i] = *reinterpret_cast<const bf16x8*>(&As[r * 64 + ((cb ^ (r & 7)) * 8)]);
            }
            #pragma unroll
            for (int j = 0; j < TN; ++j) {
                int r = wn * WTN + j * 16 + r16;
                bv[j] = *reinterpret_cast<const bf16x8*>(&Bs[r * 64 + ((cb ^ (r & 7)) * 8)]);
            }
            #pragma unroll
            for (int i = 0; i < TM; ++i)
                #pragma unroll
                for (int j = 0; j < TN; ++j)
                    acc[i][j] = __builtin_amdgcn_mfma_f32_16x16x32_bf16(av[i], bv[j], acc[i][j], 0, 0, 0);
        }
        __syncthreads();
    }

    int rb = quad * 4;

    if (EPI == 4) {
        // exp + column sums only; no C store. csum layout [z][1024].
        float csl[TN];
        #pragma unroll
        for (int j = 0; j < TN; ++j) csl[j] = 0.f;
        #pragma unroll
        for (int i = 0; i < TM; ++i)
            #pragma unroll
            for (int j = 0; j < TN; ++j)
                #pragma unroll
                for (int r = 0; r < 4; ++r)
                    csl[j] += __expf(acc[i][j][r] * alpha);
        #pragma unroll
        for (int j = 0; j < TN; ++j) {
            float cs = csl[j];
            cs += __shfl_xor(cs, 16, 64);
            cs += __shfl_xor(cs, 32, 64);
            if (quad == 0) {
                long col = bn0 + wn * WTN + j * 16 + r16;
                atomicAdd(&csum[((long)zo * zin + zi) * 1024 + col], cs);
            }
        }
        return;
    }

    // ---- LDS-staged store epilogue ----
    constexpr int EB = OUT_BF16 ? 2 : 4;
    constexpr int CH = 16 / EB;
    constexpr int STRIDE = BN + CH;
    constexpr int LDSB = (BM + BN) * BK * 2;
    constexpr int EPASS = (BM * STRIDE * EB > LDSB) ? 2 : 1;
    constexpr int RPP = BM / EPASS;
    static_assert(RPP * STRIDE * EB <= LDSB, "epilogue tile overflows LDS");
    static_assert(EPASS == 1 || (WM == 2 && WTM == RPP), "pass/wave row alignment");
    constexpr int CPR = BN / CH;
    constexpr int NCH = RPP * CPR / 256;
    static_assert(RPP * CPR % 256 == 0, "store mapping");

    float* Ef = reinterpret_cast<float*>(smem);
    char* Cb = reinterpret_cast<char*>(Cv);

    for (int pass = 0; pass < EPASS; ++pass) {
        int p0 = pass * RPP;
        __syncthreads();
        #pragma unroll
        for (int i = 0; i < TM; ++i) {
            #pragma unroll
            for (int j = 0; j < TN; ++j) {
                int lcol = wn * WTN + j * 16 + r16;
                float bsv = (EPI == 1 || EPI == 2) ? bias[bn0 + lcol] : 0.f;
                #pragma unroll
                for (int r = 0; r < 4; ++r) {
                    int lrow = wm * WTM + i * 16 + rb + r;
                    if ((unsigned)(lrow - p0) < (unsigned)RPP) {
                        float v = acc[i][j][r] * alpha;
                        if (EPI == 1) { v += bsv; v = v > 0.f ? v : 0.f; }
                        else if (EPI == 2) { v += bsv; }
                        if (OUT_BF16) smem[(lrow - p0) * STRIDE + lcol] = f2bf(v);
                        else          Ef[(lrow - p0) * STRIDE + lcol] = v;
                    }
                }
            }
        }
        __syncthreads();
        #pragma unroll
        for (int c = 0; c < NCH; ++c) {
            int cid = tid + c * 256;
            int row = cid / CPR, ch = cid - row * CPR;
            int4 v = *reinterpret_cast<const int4*>(
                reinterpret_cast<const char*>(smem) + (row * STRIDE + ch * CH) * EB);
            long gidx = coff + (bm0 + p0 + row) * ldc + bn0 + ch * CH;
            *reinterpret_cast<int4*>(Cb + gidx * EB) = v;
        }
    }
}

// ---------------- 8-phase 256x256 GEMM ----------------
// C[4096][NT*256] = alpha * A[4096][K] x B[NT*256][K]^T (+bias/relu), KS-way split-K.
// 512 thr / 8 waves (2M x 4N); per-wave C = 2 ih-blocks(64 rows) x 2 jh-blocks(32 cols).
// LDS 128KB: 2 bufs x (A 256x64 + B 256x64) bf16, stripe-XOR-swizzled (gl_lds-linear).
// Per K-tile t, 4 phases = (ih,jh) quadrants x K=64, 2 raw barriers each:
//   ph1: read av(ih0),bv(jh0) | stage (t+1).A-half1 | vmcnt(10)
//   ph2: read bv(jh1)         | stage (t+2).A-half0 | vmcnt(10)
//   ph3: read av(ih1)         | stage (t+2).B-half0 |
//   ph4:                      | stage (t+2).B-half1 | vmcnt(10)
// 2 loads/thread per half-tile; 5 half-tiles (10 loads) stay in flight. Regions are
// safe: each stage targets an LDS half whose last reader finished >=1 barrier earlier.
// Tail tiles T-2/T-1 use derived counts 10/8/4 and 2/0.

__device__ __forceinline__ void bar_raw() {
    asm volatile("" ::: "memory");
    __builtin_amdgcn_s_barrier();
    asm volatile("" ::: "memory");
}

template<int N> __device__ __forceinline__ void vmw() {
    if constexpr (N == 10) asm volatile("s_waitcnt vmcnt(10)" ::: "memory");
    else if constexpr (N == 8) asm volatile("s_waitcnt vmcnt(8)" ::: "memory");
    else if constexpr (N == 4) asm volatile("s_waitcnt vmcnt(4)" ::: "memory");
    else if constexpr (N == 2) asm volatile("s_waitcnt vmcnt(2)" ::: "memory");
    else if constexpr (N == 0) asm volatile("s_waitcnt vmcnt(0)" ::: "memory");
}

// stage one half-tile (16 stripes of 8 rows x 64 cols) = 2 gl_lds per thread
__device__ __forceinline__ void stage_half(const u16* __restrict__ base, long ld, int kt,
                                           u16* __restrict__ lds, int half, int wave) {
    const u16* src = base + (long)kt * 64;
    #pragma unroll
    for (int u = 0; u < 2; ++u) {
        int s = half * 16 + u * 8 + wave;
        gl_lds16(src + (long)(s * 8) * ld, lds + s * 512);
    }
}

template<int IH>
__device__ __forceinline__ void read_a8(bf16x8 (&av)[4][2], const u16* __restrict__ As,
                                        int wm, int r16, int quad) {
    #pragma unroll
    for (int ii = 0; ii < 4; ++ii) {
        int r = IH * 128 + wm * 64 + ii * 16 + r16;
        #pragma unroll
        for (int kx = 0; kx < 2; ++kx)
            av[ii][kx] = *reinterpret_cast<const bf16x8*>(&As[r * 64 + (((kx * 4 + quad) ^ (r & 7)) * 8)]);
    }
}

template<int JH>
__device__ __forceinline__ void read_b8(bf16x8 (&bv)[2][2], const u16* __restrict__ Bs,
                                        int wn, int r16, int quad) {
    #pragma unroll
    for (int j = 0; j < 2; ++j) {
        int r = JH * 128 + wn * 32 + j * 16 + r16;
        #pragma unroll
        for (int kx = 0; kx < 2; ++kx)
            bv[j][kx] = *reinterpret_cast<const bf16x8*>(&Bs[r * 64 + (((kx * 4 + quad) ^ (r & 7)) * 8)]);
    }
}

template<int IH, int JH>
__device__ __forceinline__ void mfma_q(f32x4 (&acc)[2][4][2][2],
                                       const bf16x8 (&av)[4][2], const bf16x8 (&bv)[2][2]) {
    #pragma unroll
    for (int kx = 0; kx < 2; ++kx)
        #pragma unroll
        for (int ii = 0; ii < 4; ++ii)
            #pragma unroll
            for (int j = 0; j < 2; ++j)
                acc[IH][ii][JH][j] = __builtin_amdgcn_mfma_f32_16x16x32_bf16(
                    av[ii][kx], bv[j][kx], acc[IH][ii][JH][j], 0, 0, 0);
}

// MODE 0: steady; 1: t=T-2 (only (t+1).A1 staged); 2: t=T-1 (no staging)
template<int MODE>
__device__ __forceinline__ void tile_iter(
    int t, f32x4 (&acc)[2][4][2][2], bf16x8 (&av)[4][2], bf16x8 (&bvh)[2][2][2],
    u16* __restrict__ smem, const u16* __restrict__ Ab, long lda,
    const u16* __restrict__ Bb, long ldb, int wave, int wm, int wn, int r16, int quad)
{
    u16* As0 = smem + (t & 1) * 32768;          // buf for tile t (also target of t+2 stages)
    u16* Bs0 = As0 + 16384;
    u16* As1 = smem + ((t + 1) & 1) * 32768;    // buf for tile t+1
    // ---- ph1 (ih0,jh0)
    read_a8<0>(av, As0, wm, r16, quad);
    read_b8<0>(bvh[0], Bs0, wn, r16, quad);
    if (MODE < 2) stage_half(Ab, lda, t + 1, As1, 1, wave);
    vmw<MODE == 0 ? 10 : (MODE == 1 ? 10 : 2)>();
    bar_raw(); __builtin_amdgcn_sched_barrier(0);
    __builtin_amdgcn_s_setprio(1);
    mfma_q<0, 0>(acc, av, bvh[0]);
    __builtin_amdgcn_s_setprio(0);
    __builtin_amdgcn_sched_barrier(0);
    bar_raw();
    // ---- ph2 (ih0,jh1)
    read_b8<1>(bvh[1], Bs0, wn, r16, quad);
    if (MODE == 0) stage_half(Ab, lda, t + 2, As0, 0, wave);
    vmw<MODE == 0 ? 10 : (MODE == 1 ? 8 : 0)>();
    bar_raw(); __builtin_amdgcn_sched_barrier(0);
    __builtin_amdgcn_s_setprio(1);
    mfma_q<0, 1>(acc, av, bvh[1]);
    __builtin_amdgcn_s_setprio(0);
    __builtin_amdgcn_sched_barrier(0);
    bar_raw();
    // ---- ph3 (ih1,jh0)
    read_a8<1>(av, As0, wm, r16, quad);
    if (MODE == 0) stage_half(Bb, ldb, t + 2, Bs0, 0, wave);
    bar_raw(); __builtin_amdgcn_sched_barrier(0);
    __builtin_amdgcn_s_setprio(1);
    mfma_q<1, 0>(acc, av, bvh[0]);
    __builtin_amdgcn_s_setprio(0);
    __builtin_amdgcn_sched_barrier(0);
    bar_raw();
    // ---- ph4 (ih1,jh1)
    if (MODE == 0) stage_half(Bb, ldb, t + 2, Bs0, 1, wave);
    if (MODE < 2) vmw<MODE == 0 ? 10 : 4>();
    bar_raw(); __builtin_amdgcn_sched_barrier(0);
    __builtin_amdgcn_s_setprio(1);
    mfma_q<1, 1>(acc, av, bvh[1]);
    __builtin_amdgcn_s_setprio(0);
    __builtin_amdgcn_sched_barrier(0);
    bar_raw();
}

// grid = 16*NT*KS blocks of 512. EPI: 0 none, 1 bias+relu. KS>1: z picks K-chunk,
// output slab z: z<2 -> Cv + (z&1)*czs, z>=2 -> Cv2 + (z&1)*czs (fp32).
template<int NT, int KS, int EPI, int OUT_BF16>
__global__ __launch_bounds__(512, 2) void gemm8_k(
    const u16* __restrict__ A, long lda,
    const u16* __restrict__ B, long ldb,
    void* __restrict__ Cv, void* __restrict__ Cv2, long ldc,
    int K, float alpha, const float* __restrict__ bias, long czs)
{
    __shared__ __align__(16) u16 smem[65536];   // 128 KiB

    int L = blockIdx.x;
    int z = 0;
    if (KS > 1) { z = L / (16 * NT); L -= z * 16 * NT; }
    int by = (L & 7) * 2 + ((L >> 3) & 1);      // XCD-contiguous M-rows
    int bx = L >> 4;
    if (KS > 1) { A += (long)z * K; B += (long)z * K; }

    int tid = threadIdx.x;
    int lane = tid & 63, wave = tid >> 6;
    int wm = wave >> 2, wn = wave & 3;
    int r16 = lane & 15, quad = lane >> 4, l8 = lane >> 3;
    int gsw = ((lane & 7) ^ l8) * 8;
    long bm0 = (long)by * 256, bn0 = (long)bx * 256;
    const u16* Ab = A + (bm0 + l8) * lda + gsw;
    const u16* Bb = B + (bn0 + l8) * ldb + gsw;

    f32x4 acc[2][4][2][2];
    #pragma unroll
    for (int a0 = 0; a0 < 2; ++a0)
        #pragma unroll
        for (int a1 = 0; a1 < 4; ++a1)
            #pragma unroll
            for (int a2 = 0; a2 < 2; ++a2)
                #pragma unroll
                for (int a3 = 0; a3 < 2; ++a3) {
                    acc[a0][a1][a2][a3][0] = 0.f; acc[a0][a1][a2][a3][1] = 0.f;
                    acc[a0][a1][a2][a3][2] = 0.f; acc[a0][a1][a2][a3][3] = 0.f;
                }
    bf16x8 av[4][2];
    bf16x8 bvh[2][2][2];

    int T = K >> 6;   // >= 3

    // prologue issue stream: [0.A0, 0.B0, 0.B1, 0.A1, 1.A0, 1.B0, 1.B1]
    stage_half(Ab, lda, 0, smem,         0, wave);
    stage_half(Bb, ldb, 0, smem + 16384, 0, wave);
    stage_half(Bb, ldb, 0, smem + 16384, 1, wave);
    stage_half(Ab, lda, 0, smem,         1, wave);
    stage_half(Ab, lda, 1, smem + 32768, 0, wave);
    stage_half(Bb, ldb, 1, smem + 49152, 0, wave);
    stage_half(Bb, ldb, 1, smem + 49152, 1, wave);
    vmw<10>();          // 14 issued -> oldest 4 (0.A0,0.B0) landed
    bar_raw();

    for (int t = 0; t < T - 2; ++t)
        tile_iter<0>(t, acc, av, bvh, smem, Ab, lda, Bb, ldb, wave, wm, wn, r16, quad);
    tile_iter<1>(T - 2, acc, av, bvh, smem, Ab, lda, Bb, ldb, wave, wm, wn, r16, quad);
    tile_iter<2>(T - 1, acc, av, bvh, smem, Ab, lda, Bb, ldb, wave, wm, wn, r16, quad);

    // ---- epilogue: stage to LDS (row-XOR-swizzled), coalesced int4 stores
    constexpr int EB = OUT_BF16 ? 2 : 4;
    constexpr int EPASS = OUT_BF16 ? 1 : 2;   // f32 = 2 passes of 128 rows (ih=pass)
    char* Cb = reinterpret_cast<char*>((KS > 1 && z >= 2) ? Cv2 : Cv);
    if (KS > 1) Cb += (long)(z & 1) * czs * EB;
    float bsv[2][2];
    if (EPI == 1) {
        #pragma unroll
        for (int jh = 0; jh < 2; ++jh)
            #pragma unroll
            for (int j = 0; j < 2; ++j)
                bsv[jh][j] = bias[bn0 + jh * 128 + wn * 32 + j * 16 + r16];
    }
    u16* sm16 = smem;
    float* smf = reinterpret_cast<float*>(smem);
    #pragma unroll
    for (int pass = 0; pass < EPASS; ++pass) {
        bar_raw();
        #pragma unroll
        for (int ih = 0; ih < 2; ++ih) {
            if (EPASS == 2 && ih != pass) continue;
            #pragma unroll
            for (int ii = 0; ii < 4; ++ii)
                #pragma unroll
                for (int jh = 0; jh < 2; ++jh)
                    #pragma unroll
                    for (int j = 0; j < 2; ++j)
                        #pragma unroll
                        for (int r = 0; r < 4; ++r) {
                            int lrow = (EPASS == 2 ? 0 : ih * 128) + wm * 64 + ii * 16 + quad * 4 + r;
                            int lcol = jh * 128 + wn * 32 + j * 16 + r16;
                            float v = acc[ih][ii][jh][j][r] * alpha;
                            if (EPI == 1) { v += bsv[jh][j]; v = v > 0.f ? v : 0.f; }
                            int scol = lcol ^ ((lrow & 7) * 8);
                            if (OUT_BF16) sm16[lrow * 256 + scol] = f2bf(v);
                            else          smf[lrow * 256 + scol] = v;
                        }
        }
        bar_raw();
        constexpr int CH = 16 / EB;
        constexpr int CPR = 256 / CH;
        constexpr int NCH = (OUT_BF16 ? 256 : 128) * CPR / 512;
        #pragma unroll
        for (int c = 0; c < NCH; ++c) {
            int cid = tid + c * 512;
            int row = cid / CPR, ch = cid - row * CPR;
            int col = (ch * CH) ^ ((row & 7) * 8);
            int4 v = *reinterpret_cast<const int4*>(
                reinterpret_cast<const char*>(smem) + ((long)row * 256 + col) * EB);
            long grow = bm0 + pass * 128 + row;
            *reinterpret_cast<int4*>(Cb + (grow * ldc + bn0 + ch * CH) * EB) = v;
        }
    }
}

// ---------------- fused attention PV: recompute E per tile, x scaled V ----------------
// Grid 512 blocks: L -> xcd=L&7: head=(L&7)*2+((L>>3)&1), tb=(L>>4)&7, b=L>>7.
// Per block: out[128 t][64 v] = sum_s exp(0.125*Q K^T) * Vt_scaled.
__global__ __launch_bounds__(256) void attn_pv_k(
    const u16* __restrict__ Qg, long ldq, long qbz,
    const u16* __restrict__ Kg, long ldk, long kbz,
    const u16* __restrict__ Vg,            // [b][1024 hv][1024 s], pre-scaled by 1/l
    u16* __restrict__ outg)                // part: [b][1024 t][1024 (h*64+v)]
{
    __shared__ __align__(16) u16 Qs[128 * 64];
    __shared__ __align__(16) u16 Ks[64 * 64];
    __shared__ __align__(16) u16 Vs[64 * 64];
    __shared__ __align__(16) u16 Es[128 * 64];

    int L = blockIdx.x;
    int h  = (L & 7) * 2 + ((L >> 3) & 1);
    int tb = (L >> 4) & 7;
    int b  = L >> 7;

    const u16* Q  = Qg + (long)b * qbz + h * 64;
    const u16* Kp = Kg + (long)b * kbz + h * 64;
    const u16* Vp = Vg + (long)b * 1048576 + (long)h * 65536;
    u16* outp = outg + (long)b * 1048576 + (long)tb * 131072 + h * 64;

    int tid = threadIdx.x, lane = tid & 63, wave = tid >> 6;
    int wm = wave >> 1, wn = wave & 1;
    int r16 = lane & 15, quad = lane >> 4, l8 = lane >> 3;
    int gsw = ((lane & 7) ^ l8) * 8;
    long t0 = (long)tb * 128;

    #pragma unroll
    for (int s = wave; s < 16; s += 4)
        gl_lds16(&Q[(t0 + s * 8 + l8) * ldq + gsw], &Qs[s * 512]);

    f32x4 acc[4][2];
    #pragma unroll
    for (int i = 0; i < 4; ++i)
        #pragma unroll
        for (int j = 0; j < 2; ++j) {
            acc[i][j][0] = 0.f; acc[i][j][1] = 0.f;
            acc[i][j][2] = 0.f; acc[i][j][3] = 0.f;
        }

    for (int sc = 0; sc < 16; ++sc) {
        #pragma unroll
        for (int s = wave; s < 8; s += 4) {
            gl_lds16(&Kp[(long)(sc * 64 + s * 8 + l8) * ldk + gsw], &Ks[s * 512]);
            gl_lds16(&Vp[(long)(s * 8 + l8) * 1024 + sc * 64 + gsw], &Vs[s * 512]);
        }
        __syncthreads();                       // K/V (and Q on sc==0) staged

        // E-chunk = Q x K^T (128x64, contraction 64)
        f32x4 e[4][2];
        #pragma unroll
        for (int i = 0; i < 4; ++i)
            #pragma unroll
            for (int j = 0; j < 2; ++j) {
                e[i][j][0] = 0.f; e[i][j][1] = 0.f;
                e[i][j][2] = 0.f; e[i][j][3] = 0.f;
            }
        #pragma unroll
        for (int kk = 0; kk < 64; kk += 32) {
            int cb = (kk >> 3) + quad;
            bf16x8 av[4], bv[2];
            #pragma unroll
            for (int i = 0; i < 4; ++i) {
                int r = wm * 64 + i * 16 + r16;
                av[i] = *reinterpret_cast<const bf16x8*>(&Qs[r * 64 + ((cb ^ (r & 7)) * 8)]);
            }
            #pragma unroll
            for (int j = 0; j < 2; ++j) {
                int r = wn * 32 + j * 16 + r16;
                bv[j] = *reinterpret_cast<const bf16x8*>(&Ks[r * 64 + ((cb ^ (r & 7)) * 8)]);
            }
            #pragma unroll
            for (int i = 0; i < 4; ++i)
                #pragma unroll
                for (int j = 0; j < 2; ++j)
                    e[i][j] = __builtin_amdgcn_mfma_f32_16x16x32_bf16(av[i], bv[j], e[i][j], 0, 0, 0);
        }
        // exp + write to Es (C-frag: row=quad*4+r, col=r16; XOR-swizzled rows)
        #pragma unroll
        for (int i = 0; i < 4; ++i)
            #pragma unroll
            for (int j = 0; j < 2; ++j) {
                int lcol = wn * 32 + j * 16 + r16;
                #pragma unroll
                for (int r = 0; r < 4; ++r) {
                    int lrow = wm * 64 + i * 16 + quad * 4 + r;
                    float v = __expf(e[i][j][r] * 0.125f);
                    Es[lrow * 64 + (((lcol >> 3) ^ (lrow & 7)) * 8) + (lcol & 7)] = f2bf(v);
                }
            }
        __syncthreads();                       // Es ready

        // acc += E-chunk x Vs^T (contraction over s-chunk)
        #pragma unroll
        for (int kk = 0; kk < 64; kk += 32) {
            int cb = (kk >> 3) + quad;
            bf16x8 av[4], bv[2];
            #pragma unroll
            for (int i = 0; i < 4; ++i) {
                int r = wm * 64 + i * 16 + r16;
                av[i] = *reinterpret_cast<const bf16x8*>(&Es[r * 64 + ((cb ^ (r & 7)) * 8)]);
            }
            #pragma unroll
            for (int j = 0; j < 2; ++j) {
                int r = wn * 32 + j * 16 + r16;
                bv[j] = *reinterpret_cast<const bf16x8*>(&Vs[r * 64 + ((cb ^ (r & 7)) * 8)]);
            }
            #pragma unroll
            for (int i = 0; i < 4; ++i)
                #pragma unroll
                for (int j = 0; j < 2; ++j)
                    acc[i][j] = __builtin_amdgcn_mfma_f32_16x16x32_bf16(av[i], bv[j], acc[i][j], 0, 0, 0);
        }
        __syncthreads();                       // PV done; next stage may overwrite K/V
    }

    #pragma unroll
    for (int i = 0; i < 4; ++i)
        #pragma unroll
        for (int j = 0; j < 2; ++j) {
            int lcol = wn * 32 + j * 16 + r16;
            #pragma unroll
            for (int r = 0; r < 4; ++r) {
                int lrow = wm * 64 + i * 16 + quad * 4 + r;
                outp[(long)lrow * 1024 + lcol] = f2bf(acc[i][j][r]);
            }
        }
}

// ---------------- Vt *= 1/l over all 4 batches: csum [4][16][1024] ----------------
__global__ __launch_bounds__(256) void vscale_k(u16* __restrict__ Vt, const float* __restrict__ csum) {
    long idx = (long)blockIdx.x * 256 + threadIdx.x;   // grid 2048
    int slab = (int)(idx >> 17);
    int rem = (int)(idx & 131071);
    int hv = rem >> 7;
    int s8 = (rem & 127) * 8;
    const float* cs = csum + slab * 16384 + (hv >> 6) * 1024 + s8;
    u16* pv = Vt + (long)slab * 1048576 + (long)hv * 1024 + s8;
    ushort4 a = *reinterpret_cast<ushort4*>(pv);
    ushort4 b = *reinterpret_cast<ushort4*>(pv + 4);
    a.x = f2bf(bf2f(a.x) / cs[0]); a.y = f2bf(bf2f(a.y) / cs[1]);
    a.z = f2bf(bf2f(a.z) / cs[2]); a.w = f2bf(bf2f(a.w) / cs[3]);
    b.x = f2bf(bf2f(b.x) / cs[4]); b.y = f2bf(bf2f(b.y) / cs[5]);
    b.z = f2bf(bf2f(b.z) / cs[6]); b.w = f2bf(bf2f(b.w) / cs[7]);
    *reinterpret_cast<ushort4*>(pv) = a;
    *reinterpret_cast<ushort4*>(pv + 4) = b;
}

// ---------------- out = (sum of NP partial slabs + resid [+bias]) - mean - std ----------------
// Slabs 0,1 from parts; slabs 2,3 (NP=4) from parts2.
template<int NP, int BIAS>
__global__ __launch_bounds__(256) void addsn_k(const float* __restrict__ parts,
                                               const float* __restrict__ parts2,
                                               long pstride,
                                               const float* __restrict__ resid,
                                               const float* __restrict__ bias,
                                               float* __restrict__ out) {
    __shared__ float sm[8];
    long row = blockIdx.x;
    int tid = threadIdx.x;
    float4 x = reinterpret_cast<const float4*>(resid + row * 1024)[tid];
    #pragma unroll
    for (int p = 0; p < NP; ++p) {
        const float* src = (p < 2) ? (parts + p * pstride) : (parts2 + (p - 2) * pstride);
        float4 a = reinterpret_cast<const float4*>(src + row * 1024)[tid];
        x.x += a.x; x.y += a.y; x.z += a.z; x.w += a.w;
    }
    if (BIAS) {
        float4 bb = reinterpret_cast<const float4*>(bias)[tid];
        x.x += bb.x; x.y += bb.y; x.z += bb.z; x.w += bb.w;
    }
    float s = x.x + x.y + x.z + x.w;
    for (int o = 32; o > 0; o >>= 1) s += __shfl_down(s, o, 64);
    int lane = tid & 63, w = tid >> 6;
    if (lane == 0) sm[w] = s;
    __syncthreads();
    float mean = (sm[0] + sm[1] + sm[2] + sm[3]) * (1.f / 1024.f);
    float d0 = x.x - mean, d1 = x.y - mean, d2 = x.z - mean, d3 = x.w - mean;
    float q = d0 * d0 + d1 * d1 + d2 * d2 + d3 * d3;
    for (int o = 32; o > 0; o >>= 1) q += __shfl_down(q, o, 64);
    if (lane == 0) sm[w + 4] = q;
    __syncthreads();
    float sd = sqrtf((sm[4] + sm[5] + sm[6] + sm[7]) * (1.f / 1023.f));
    float4 ov;
    ov.x = d0 - sd; ov.y = d1 - sd; ov.z = d2 - sd; ov.w = d3 - sd;
    reinterpret_cast<float4*>(out + row * 1024)[tid] = ov;
}

// ---------------- launcher ----------------

extern "C" void kernel_launch(void* const* d_in, const int* in_sizes, int n_in,
                              void* d_out, int out_size, void* d_ws, size_t ws_size,
                              hipStream_t stream) {
    (void)in_sizes; (void)n_in; (void)out_size; (void)ws_size;
    const float* xf   = (const float*)d_in[0];
    const float* yf   = (const float*)d_in[1];
    const float* Wq1  = (const float*)d_in[2];
    const float* Wk1  = (const float*)d_in[3];
    const float* Wv1  = (const float*)d_in[4];
    const float* Wo1  = (const float*)d_in[5];
    const float* Wq2  = (const float*)d_in[6];
    const float* Wk2  = (const float*)d_in[7];
    const float* Wv2  = (const float*)d_in[8];
    const float* Wo2  = (const float*)d_in[9];
    const float* W_in = (const float*)d_in[10];
    const float* b_in = (const float*)d_in[11];
    const float* W_out= (const float*)d_in[12];
    const float* b_out= (const float*)d_in[13];

    // workspace layout (~192 MB)
    char* p = (char*)d_ws;
    auto alloc = [&](size_t bytes) { char* r = p; p += bytes; return r; };
    u16*   yb    = (u16*)alloc(8388608);    // y bf16 (4096x1024)
    u16*   xb    = (u16*)alloc(8388608);    // x bf16
    u16*   W1cat = (u16*)alloc(8388608);    // [Wq1|Wk1|Wv1|Wq2]^T-packed (4096 x 1024)
    u16*   Wkv2t = (u16*)alloc(4194304);    // [Wk2|Wv2] (2048 x 1024)
    u16*   Wo1t  = (u16*)alloc(2097152);
    u16*   Wo2t  = (u16*)alloc(2097152);
    u16*   Winb  = (u16*)alloc(8388608);    // W_in (4096 x 1024) = Bt layout
    u16*   Woutb = (u16*)alloc(8388608);    // W_out (1024 x 4096) = Bt layout
    u16*   QKV   = (u16*)alloc(33554432);   // (4096 x 4096): [Q1|K1|V1|Q2] per (b,t);
                                            // dead after MHA2 -> reused as FFN-out fp32 slabs 2,3
    u16*   KV2   = (u16*)alloc(16777216);   // (4096 x 2048): [K2|V2]
    u16*   Vt    = (u16*)alloc(8388608);    // per b: (1024 hv x 1024 s), scaled by 1/l in place
    u16*   Pb    = (u16*)alloc(33554432);   // FFN hidden (4096x4096 bf16)
    float* csum  = (float*)alloc(262144);   // column sums l [4][16][1024]
    u16*   part  = (u16*)alloc(8388608);    // attn partial (4096 x 1024) bf16
    float* gout  = (float*)alloc(33554432); // fp32 split-K partials, 2 slabs of 16 MB
    float* out1  = (float*)alloc(16777216);

    // ---- converts + weight packs ----
    convert_f2b_k<<<4096, 256, 0, stream>>>(yf, yb);
    convert_f2b_k<<<4096, 256, 0, stream>>>(xf, xb);
    pack_perm_t<<<dim3(1, 16, 16), 256, 0, stream>>>(Wq1, W1cat,           1024, 64);
    pack_perm_t<<<dim3(1, 16, 16), 256, 0, stream>>>(Wk1, W1cat + 1048576, 1024, 64);
    pack_perm_t<<<dim3(1, 16, 16), 256, 0, stream>>>(Wv1, W1cat + 2097152, 1024, 64);
    pack_perm_t<<<dim3(1, 16, 16), 256, 0, stream>>>(Wq2, W1cat + 3145728, 1024, 64);
    pack_perm_t<<<dim3(1, 16, 16), 256, 0, stream>>>(Wk2, Wkv2t,           1024, 64);
    pack_perm_t<<<dim3(1, 16, 16), 256, 0, stream>>>(Wv2, Wkv2t + 1048576, 1024, 64);
    pack_perm_t<<<dim3(16, 16, 1), 256, 0, stream>>>(Wo1, Wo1t,            1024, 1024);
    pack_perm_t<<<dim3(16, 16, 1), 256, 0, stream>>>(Wo2, Wo2t,            1024, 1024);
    convert_f2b_k<<<4096, 256, 0, stream>>>(W_in,  Winb);
    convert_f2b_k<<<4096, 256, 0, stream>>>(W_out, Woutb);

    // attention core: all 4 batches per dispatch.
    auto run_attention = [&](const u16* Q, long ldq, long qbz,
                             const u16* Kp, long ldk, long kbz,
                             const u16* Vp, long ldv, long vbz) {
        transpose_k<<<dim3(16, 16, 4), 256, 0, stream>>>(Vp, ldv, vbz, Vt, 1024L, 1048576L);
        hipMemsetAsync(csum, 0, 262144, stream);
        // l-pass: exp column-sums, no stores. z=(b,h): zi=h (stride 64), zo=b.
        gemm_k<128,128,64,2,2,1,4,0,1><<<dim3(8, 8, 64), 256, 0, stream>>>(
            Q, ldq, 64L, qbz, Kp, ldk, 64L, kbz,
            (void*)Pb, 1024L, 0L, 0L, 16, 64, 0.125f, nullptr, csum);
        vscale_k<<<2048, 256, 0, stream>>>(Vt, csum);
        attn_pv_k<<<512, 256, 0, stream>>>(Q, ldq, qbz, Kp, ldk, kbz, Vt, part);
    };

    // ---- fused projections (8-phase 256^2): QKV1 + Q2 from y (N=4096) ----
    gemm8_k<16,1,0,1><<<256, 512, 0, stream>>>(
        yb, 1024L, W1cat, 1024L, (void*)QKV, nullptr, 4096L, 1024, 1.0f, nullptr, 0L);
    // K2/V2 from x, N=2048
    gemm8_k<8,1,0,1><<<128, 512, 0, stream>>>(
        xb, 1024L, Wkv2t, 1024L, (void*)KV2, nullptr, 2048L, 1024, 1.0f, nullptr, 0L);

    // ---- MHA1 (self-attn on y): Q/K/V at cols 0/1024/2048 of QKV ----
    run_attention(QKV, 4096L, 4194304L, QKV + 1024, 4096L, 4194304L, QKV + 2048, 4096L, 4194304L);
    gemm_k<128,64,64,2,2,0,0,4,2><<<dim3(2 * 512), 256, 0, stream>>>(
        part, 1024L, 0L, 512L, Wo1t, 1024L, 0L, 512L,
        (void*)gout, 1024L, 0L, 4194304L, 1, 512, 1.0f, nullptr, nullptr);
    addsn_k<2,0><<<4096, 256, 0, stream>>>(gout, nullptr, 4194304L, yf, nullptr, out1);

    // ---- MHA2 (q from y at QKV col 3072; k/v from x in KV2) ----
    run_attention(QKV + 3072, 4096L, 4194304L, KV2, 2048L, 2097152L, KV2 + 1024, 2048L, 2097152L);
    gemm_k<128,64,64,2,2,0,0,4,2><<<dim3(2 * 512), 256, 0, stream>>>(
        part, 1024L, 0L, 512L, Wo2t, 1024L, 0L, 512L,
        (void*)gout, 1024L, 0L, 4194304L, 1, 512, 1.0f, nullptr, nullptr);
    addsn_k<2,0><<<4096, 256, 0, stream>>>(gout, nullptr, 4194304L, out1, nullptr, (float*)d_out);

    // ---- FFN on y (hidden in Pb: 4096x4096 bf16), 8-phase GEMMs ----
    gemm8_k<16,1,1,1><<<256, 512, 0, stream>>>(
        yb, 1024L, Winb, 1024L, (void*)Pb, nullptr, 4096L, 1024, 1.0f, b_in, 0L);
    // FFN-out: split-K 4 (full machine); slabs 0,1 -> gout, slabs 2,3 -> dead QKV region
    gemm8_k<4,4,0,0><<<256, 512, 0, stream>>>(
        Pb, 4096L, Woutb, 4096L, (void*)gout, (void*)QKV, 1024L, 1024, 1.0f, nullptr, 4194304L);
    addsn_k<4,1><<<4096, 256, 0, stream>>>(gout, (const float*)QKV, 4194304L,
                                           (const float*)d_out, b_out, (float*)d_out);
}

// Round 2
// 516.344 us; speedup vs baseline: 1.0221x; 1.0039x over previous
//
#include <hip/hip_runtime.h>

// DecoderStack: B=4,T=1024,D=1024,H=16,DK=DV=64,FF=4096
// Softmax over QUERY axis: l_s = sum_t exp(S) via store-free l-pass (EPI=4),
// 1/l_s folded into V (vscale), then fused attn_pv_k recomputes E per tile in
// LDS and multiplies by V — E never touches HBM.
// sub_norm(o) = o - mean - std (ddof=1).
// gemm8_k: 256x256 tile, 8 waves, 4-phase-per-K-tile schedule, counted
// vmcnt(10) (never drains in main loop), raw s_barriers, setprio around MFMA.
// R2: sched_barrier(0) pins REMOVED (m141: order-pinning defeats compiler
// scheduling, -40%); barriers + vmcnt + asm memory clobbers carry correctness.

typedef unsigned short u16;
typedef __bf16 bf16x8 __attribute__((ext_vector_type(8)));
typedef float f32x4 __attribute__((ext_vector_type(4)));

__device__ __forceinline__ u16 f2bf(float f) {
    unsigned int u = __float_as_uint(f);
    u += 0x7fffu + ((u >> 16) & 1u);   // RNE; inputs are finite
    return (u16)(u >> 16);
}
__device__ __forceinline__ float bf2f(u16 b) {
    return __uint_as_float(((unsigned int)b) << 16);
}

typedef __attribute__((address_space(1))) const void* as1cv;
typedef __attribute__((address_space(3))) void* as3v;
__device__ __forceinline__ void gl_lds16(const void* g, void* l) {
    __builtin_amdgcn_global_load_lds((as1cv)g, (as3v)l, 16, 0, 0);
}

// ---------------- converts / packs ----------------

__global__ __launch_bounds__(256) void convert_f2b_k(const float* __restrict__ in, u16* __restrict__ out) {
    long i = (long)blockIdx.x * 256 + threadIdx.x;
    float4 v = reinterpret_cast<const float4*>(in)[i];
    ushort4 o;
    o.x = f2bf(v.x); o.y = f2bf(v.y); o.z = f2bf(v.z); o.w = f2bf(v.w);
    reinterpret_cast<ushort4*>(out)[i] = o;
}

// out[p][r][q] = in[p][q][r] (fp32->bf16), LDS-tiled. grid (R/64, Q/64, P)
__global__ __launch_bounds__(256) void pack_perm_t(const float* __restrict__ in, u16* __restrict__ out,
                                                   int Q, int R) {
    __shared__ float tile[64][65];
    int p = blockIdx.z;
    int r0 = blockIdx.x * 64, q0 = blockIdx.y * 64;
    int tx = threadIdx.x & 63, ty = threadIdx.x >> 6;
    const float* inp = in + ((long)p * Q + q0) * R + r0;
    #pragma unroll
    for (int i = 0; i < 64; i += 4)
        tile[ty + i][tx] = inp[(long)(ty + i) * R + tx];
    __syncthreads();
    u16* outp = out + ((long)p * R + r0) * Q + q0;
    #pragma unroll
    for (int i = 0; i < 64; i += 4)
        outp[(long)(ty + i) * Q + tx] = f2bf(tile[tx][ty + i]);
}

// 64x64 tiled bf16 transpose: out[c][r] = in[r][c], batched over z
__global__ __launch_bounds__(256) void transpose_k(const u16* __restrict__ in, long ld_in, long z_in,
                                                   u16* __restrict__ out, long ld_out, long z_out) {
    __shared__ u16 tile[64][66];
    const u16* inz = in + (long)blockIdx.z * z_in;
    u16* outz = out + (long)blockIdx.z * z_out;
    int r0 = blockIdx.y * 64;
    int c0 = blockIdx.x * 64;
    int tx = threadIdx.x & 63, ty = threadIdx.x >> 6;
    #pragma unroll
    for (int i = 0; i < 64; i += 4)
        tile[ty + i][tx] = inz[(long)(r0 + ty + i) * ld_in + c0 + tx];
    __syncthreads();
    #pragma unroll
    for (int i = 0; i < 64; i += 4)
        outz[(long)(c0 + ty + i) * ld_out + r0 + tx] = tile[tx][ty + i];
}

// ---------------- legacy GEMM (kept for l-pass EPI=4 and small Wo split-K) ----------------
template<int BM, int BN, int BK, int WM, int WN, int OUT_BF16, int EPI, int SWZ, int KS>
__global__ __launch_bounds__(256) void gemm_k(
    const u16* __restrict__ A, long lda, long a_zin, long a_zout,
    const u16* __restrict__ B, long ldb, long b_zin, long b_zout,
    void* __restrict__ Cv, long ldc, long c_zin, long c_zout,
    int zin, int K, float alpha, const float* __restrict__ bias,
    float* __restrict__ csum)
{
    static_assert(BK == 64, "staging assumes BK=64");
    constexpr int WTM = BM / WM;
    constexpr int WTN = BN / WN;
    constexpr int TM = WTM / 16;
    constexpr int TN = WTN / 16;
    __shared__ __align__(16) u16 smem[(BM + BN) * BK];
    u16* As = smem;
    u16* Bs = smem + BM * BK;

    int bx, by, z;
    if (SWZ == 4) {
        int L = blockIdx.x;
        if (KS > 1) { z = L >> 9; L &= 511; } else { z = 0; }
        by = (L & 7) * 4 + ((L >> 3) & 3);
        bx = L >> 5;
    } else {
        bx = blockIdx.x; by = blockIdx.y; z = blockIdx.z;
    }
    int zi = z % zin, zo = z / zin;
    A += (long)zi * a_zin + (long)zo * a_zout;
    B += (long)zi * b_zin + (long)zo * b_zout;
    long coff = (long)zi * c_zin + (long)zo * c_zout;

    int tid = threadIdx.x;
    int lane = tid & 63;
    int wave = tid >> 6;
    int wm = wave / WN, wn = wave % WN;
    long bm0 = (long)by * BM, bn0 = (long)bx * BN;

    f32x4 acc[TM][TN];
    #pragma unroll
    for (int i = 0; i < TM; ++i)
        #pragma unroll
        for (int j = 0; j < TN; ++j) {
            acc[i][j][0] = 0.f; acc[i][j][1] = 0.f;
            acc[i][j][2] = 0.f; acc[i][j][3] = 0.f;
        }

    int r16 = lane & 15;
    int quad = lane >> 4;
    int l8 = lane >> 3;                    // stripe row
    int gsw = ((lane & 7) ^ l8) * 8;       // swizzled global col (elements)

    constexpr int ASTR = BM / 8;
    constexpr int BSTR = BN / 8;

    for (int k0 = 0; k0 < K; k0 += BK) {
        #pragma unroll
        for (int s = wave; s < ASTR; s += 4)
            gl_lds16(&A[(bm0 + s * 8 + l8) * lda + k0 + gsw], &As[s * 512]);
        #pragma unroll
        for (int s = wave; s < BSTR; s += 4)
            gl_lds16(&B[(bn0 + s * 8 + l8) * ldb + k0 + gsw], &Bs[s * 512]);
        __syncthreads();
        #pragma unroll
        for (int kk = 0; kk < BK; kk += 32) {
            int cb = (kk >> 3) + quad;
            bf16x8 av[TM], bv[TN];
            #pragma unroll
            for (int i = 0; i < TM; ++i) {
                int r = wm * WTM + i * 16 + r16;
                av[i] = *reinterpret_cast<const bf16x8*>(&As[r * 64 + ((cb ^ (r & 7)) * 8)]);
            }
            #pragma unroll
            for (int j = 0; j < TN; ++j) {
                int r = wn * WTN + j * 16 + r16;
                bv[j] = *reinterpret_cast<const bf16x8*>(&Bs[r * 64 + ((cb ^ (r & 7)) * 8)]);
            }
            #pragma unroll
            for (int i = 0; i < TM; ++i)
                #pragma unroll
                for (int j = 0; j < TN; ++j)
                    acc[i][j] = __builtin_amdgcn_mfma_f32_16x16x32_bf16(av[i], bv[j], acc[i][j], 0, 0, 0);
        }
        __syncthreads();
    }

    int rb = quad * 4;

    if (EPI == 4) {
        // exp + column sums only; no C store. csum layout [z][1024].
        float csl[TN];
        #pragma unroll
        for (int j = 0; j < TN; ++j) csl[j] = 0.f;
        #pragma unroll
        for (int i = 0; i < TM; ++i)
            #pragma unroll
            for (int j = 0; j < TN; ++j)
                #pragma unroll
                for (int r = 0; r < 4; ++r)
                    csl[j] += __expf(acc[i][j][r] * alpha);
        #pragma unroll
        for (int j = 0; j < TN; ++j) {
            float cs = csl[j];
            cs += __shfl_xor(cs, 16, 64);
            cs += __shfl_xor(cs, 32, 64);
            if (quad == 0) {
                long col = bn0 + wn * WTN + j * 16 + r16;
                atomicAdd(&csum[((long)zo * zin + zi) * 1024 + col], cs);
            }
        }
        return;
    }

    // ---- LDS-staged store epilogue ----
    constexpr int EB = OUT_BF16 ? 2 : 4;
    constexpr int CH = 16 / EB;
    constexpr int STRIDE = BN + CH;
    constexpr int LDSB = (BM + BN) * BK * 2;
    constexpr int EPASS = (BM * STRIDE * EB > LDSB) ? 2 : 1;
    constexpr int RPP = BM / EPASS;
    static_assert(RPP * STRIDE * EB <= LDSB, "epilogue tile overflows LDS");
    static_assert(EPASS == 1 || (WM == 2 && WTM == RPP), "pass/wave row alignment");
    constexpr int CPR = BN / CH;
    constexpr int NCH = RPP * CPR / 256;
    static_assert(RPP * CPR % 256 == 0, "store mapping");

    float* Ef = reinterpret_cast<float*>(smem);
    char* Cb = reinterpret_cast<char*>(Cv);

    for (int pass = 0; pass < EPASS; ++pass) {
        int p0 = pass * RPP;
        __syncthreads();
        #pragma unroll
        for (int i = 0; i < TM; ++i) {
            #pragma unroll
            for (int j = 0; j < TN; ++j) {
                int lcol = wn * WTN + j * 16 + r16;
                float bsv = (EPI == 1 || EPI == 2) ? bias[bn0 + lcol] : 0.f;
                #pragma unroll
                for (int r = 0; r < 4; ++r) {
                    int lrow = wm * WTM + i * 16 + rb + r;
                    if ((unsigned)(lrow - p0) < (unsigned)RPP) {
                        float v = acc[i][j][r] * alpha;
                        if (EPI == 1) { v += bsv; v = v > 0.f ? v : 0.f; }
                        else if (EPI == 2) { v += bsv; }
                        if (OUT_BF16) smem[(lrow - p0) * STRIDE + lcol] = f2bf(v);
                        else          Ef[(lrow - p0) * STRIDE + lcol] = v;
                    }
                }
            }
        }
        __syncthreads();
        #pragma unroll
        for (int c = 0; c < NCH; ++c) {
            int cid = tid + c * 256;
            int row = cid / CPR, ch = cid - row * CPR;
            int4 v = *reinterpret_cast<const int4*>(
                reinterpret_cast<const char*>(smem) + (row * STRIDE + ch * CH) * EB);
            long gidx = coff + (bm0 + p0 + row) * ldc + bn0 + ch * CH;
            *reinterpret_cast<int4*>(Cb + gidx * EB) = v;
        }
    }
}

// ---------------- 8-phase 256x256 GEMM ----------------
// C[4096][NT*256] = alpha * A[4096][K] x B[NT*256][K]^T (+bias/relu), KS-way split-K.
// 512 thr / 8 waves (2M x 4N); per-wave C = 2 ih-blocks(64 rows) x 2 jh-blocks(32 cols).
// LDS 128KB: 2 bufs x (A 256x64 + B 256x64) bf16, stripe-XOR-swizzled (gl_lds-linear).
// Per K-tile t, 4 phases = (ih,jh) quadrants x K=64, 2 raw barriers each:
//   ph1: read av(ih0),bv(jh0) | stage (t+1).A-half1 | vmcnt(10)
//   ph2: read bv(jh1)         | stage (t+2).A-half0 | vmcnt(10)
//   ph3: read av(ih1)         | stage (t+2).B-half0 |
//   ph4:                      | stage (t+2).B-half1 | vmcnt(10)
// 2 loads/thread per half-tile; 5 half-tiles (10 loads) stay in flight. Regions are
// safe: each stage targets an LDS half whose last reader finished >=1 barrier earlier.
// Tail tiles T-2/T-1 use derived counts 10/8/4 and 2/0.
// NO sched_barrier(0): compiler must be free to overlap addr-VALU / ds_read
// issue with MFMA clusters (m141: pinning costs ~40%). Barriers+vmcnt+clobbers
// carry all cross-wave ordering; MFMA->operand deps are visible dataflow.

__device__ __forceinline__ void bar_raw() {
    asm volatile("" ::: "memory");
    __builtin_amdgcn_s_barrier();
    asm volatile("" ::: "memory");
}

template<int N> __device__ __forceinline__ void vmw() {
    if constexpr (N == 10) asm volatile("s_waitcnt vmcnt(10)" ::: "memory");
    else if constexpr (N == 8) asm volatile("s_waitcnt vmcnt(8)" ::: "memory");
    else if constexpr (N == 4) asm volatile("s_waitcnt vmcnt(4)" ::: "memory");
    else if constexpr (N == 2) asm volatile("s_waitcnt vmcnt(2)" ::: "memory");
    else if constexpr (N == 0) asm volatile("s_waitcnt vmcnt(0)" ::: "memory");
}

// stage one half-tile (16 stripes of 8 rows x 64 cols) = 2 gl_lds per thread
__device__ __forceinline__ void stage_half(const u16* __restrict__ base, long ld, int kt,
                                           u16* __restrict__ lds, int half, int wave) {
    const u16* src = base + (long)kt * 64;
    #pragma unroll
    for (int u = 0; u < 2; ++u) {
        int s = half * 16 + u * 8 + wave;
        gl_lds16(src + (long)(s * 8) * ld, lds + s * 512);
    }
}

template<int IH>
__device__ __forceinline__ void read_a8(bf16x8 (&av)[4][2], const u16* __restrict__ As,
                                        int wm, int r16, int quad) {
    #pragma unroll
    for (int ii = 0; ii < 4; ++ii) {
        int r = IH * 128 + wm * 64 + ii * 16 + r16;
        #pragma unroll
        for (int kx = 0; kx < 2; ++kx)
            av[ii][kx] = *reinterpret_cast<const bf16x8*>(&As[r * 64 + (((kx * 4 + quad) ^ (r & 7)) * 8)]);
    }
}

template<int JH>
__device__ __forceinline__ void read_b8(bf16x8 (&bv)[2][2], const u16* __restrict__ Bs,
                                        int wn, int r16, int quad) {
    #pragma unroll
    for (int j = 0; j < 2; ++j) {
        int r = JH * 128 + wn * 32 + j * 16 + r16;
        #pragma unroll
        for (int kx = 0; kx < 2; ++kx)
            bv[j][kx] = *reinterpret_cast<const bf16x8*>(&Bs[r * 64 + (((kx * 4 + quad) ^ (r & 7)) * 8)]);
    }
}

template<int IH, int JH>
__device__ __forceinline__ void mfma_q(f32x4 (&acc)[2][4][2][2],
                                       const bf16x8 (&av)[4][2], const bf16x8 (&bv)[2][2]) {
    #pragma unroll
    for (int kx = 0; kx < 2; ++kx)
        #pragma unroll
        for (int ii = 0; ii < 4; ++ii)
            #pragma unroll
            for (int j = 0; j < 2; ++j)
                acc[IH][ii][JH][j] = __builtin_amdgcn_mfma_f32_16x16x32_bf16(
                    av[ii][kx], bv[j][kx], acc[IH][ii][JH][j], 0, 0, 0);
}

// MODE 0: steady; 1: t=T-2 (only (t+1).A1 staged); 2: t=T-1 (no staging)
template<int MODE>
__device__ __forceinline__ void tile_iter(
    int t, f32x4 (&acc)[2][4][2][2], bf16x8 (&av)[4][2], bf16x8 (&bvh)[2][2][2],
    u16* __restrict__ smem, const u16* __restrict__ Ab, long lda,
    const u16* __restrict__ Bb, long ldb, int wave, int wm, int wn, int r16, int quad)
{
    u16* As0 = smem + (t & 1) * 32768;          // buf for tile t (also target of t+2 stages)
    u16* Bs0 = As0 + 16384;
    u16* As1 = smem + ((t + 1) & 1) * 32768;    // buf for tile t+1
    // ---- ph1 (ih0,jh0)
    read_a8<0>(av, As0, wm, r16, quad);
    read_b8<0>(bvh[0], Bs0, wn, r16, quad);
    if (MODE < 2) stage_half(Ab, lda, t + 1, As1, 1, wave);
    vmw<MODE == 0 ? 10 : (MODE == 1 ? 10 : 2)>();
    bar_raw();
    __builtin_amdgcn_s_setprio(1);
    mfma_q<0, 0>(acc, av, bvh[0]);
    __builtin_amdgcn_s_setprio(0);
    bar_raw();
    // ---- ph2 (ih0,jh1)
    read_b8<1>(bvh[1], Bs0, wn, r16, quad);
    if (MODE == 0) stage_half(Ab, lda, t + 2, As0, 0, wave);
    vmw<MODE == 0 ? 10 : (MODE == 1 ? 8 : 0)>();
    bar_raw();
    __builtin_amdgcn_s_setprio(1);
    mfma_q<0, 1>(acc, av, bvh[1]);
    __builtin_amdgcn_s_setprio(0);
    bar_raw();
    // ---- ph3 (ih1,jh0)
    read_a8<1>(av, As0, wm, r16, quad);
    if (MODE == 0) stage_half(Bb, ldb, t + 2, Bs0, 0, wave);
    bar_raw();
    __builtin_amdgcn_s_setprio(1);
    mfma_q<1, 0>(acc, av, bvh[0]);
    __builtin_amdgcn_s_setprio(0);
    bar_raw();
    // ---- ph4 (ih1,jh1)
    if (MODE == 0) stage_half(Bb, ldb, t + 2, Bs0, 1, wave);
    if (MODE < 2) vmw<MODE == 0 ? 10 : 4>();
    bar_raw();
    __builtin_amdgcn_s_setprio(1);
    mfma_q<1, 1>(acc, av, bvh[1]);
    __builtin_amdgcn_s_setprio(0);
    bar_raw();
}

// grid = 16*NT*KS blocks of 512. EPI: 0 none, 1 bias+relu. KS>1: z picks K-chunk,
// output slab z: z<2 -> Cv + (z&1)*czs, z>=2 -> Cv2 + (z&1)*czs (fp32).
template<int NT, int KS, int EPI, int OUT_BF16>
__global__ __launch_bounds__(512, 2) void gemm8_k(
    const u16* __restrict__ A, long lda,
    const u16* __restrict__ B, long ldb,
    void* __restrict__ Cv, void* __restrict__ Cv2, long ldc,
    int K, float alpha, const float* __restrict__ bias, long czs)
{
    __shared__ __align__(16) u16 smem[65536];   // 128 KiB

    int L = blockIdx.x;
    int z = 0;
    if (KS > 1) { z = L / (16 * NT); L -= z * 16 * NT; }
    int by = (L & 7) * 2 + ((L >> 3) & 1);      // XCD-contiguous M-rows
    int bx = L >> 4;
    if (KS > 1) { A += (long)z * K; B += (long)z * K; }

    int tid = threadIdx.x;
    int lane = tid & 63, wave = tid >> 6;
    int wm = wave >> 2, wn = wave & 3;
    int r16 = lane & 15, quad = lane >> 4, l8 = lane >> 3;
    int gsw = ((lane & 7) ^ l8) * 8;
    long bm0 = (long)by * 256, bn0 = (long)bx * 256;
    const u16* Ab = A + (bm0 + l8) * lda + gsw;
    const u16* Bb = B + (bn0 + l8) * ldb + gsw;

    f32x4 acc[2][4][2][2];
    #pragma unroll
    for (int a0 = 0; a0 < 2; ++a0)
        #pragma unroll
        for (int a1 = 0; a1 < 4; ++a1)
            #pragma unroll
            for (int a2 = 0; a2 < 2; ++a2)
                #pragma unroll
                for (int a3 = 0; a3 < 2; ++a3) {
                    acc[a0][a1][a2][a3][0] = 0.f; acc[a0][a1][a2][a3][1] = 0.f;
                    acc[a0][a1][a2][a3][2] = 0.f; acc[a0][a1][a2][a3][3] = 0.f;
                }
    bf16x8 av[4][2];
    bf16x8 bvh[2][2][2];

    int T = K >> 6;   // >= 3

    // prologue issue stream: [0.A0, 0.B0, 0.B1, 0.A1, 1.A0, 1.B0, 1.B1]
    stage_half(Ab, lda, 0, smem,         0, wave);
    stage_half(Bb, ldb, 0, smem + 16384, 0, wave);
    stage_half(Bb, ldb, 0, smem + 16384, 1, wave);
    stage_half(Ab, lda, 0, smem,         1, wave);
    stage_half(Ab, lda, 1, smem + 32768, 0, wave);
    stage_half(Bb, ldb, 1, smem + 49152, 0, wave);
    stage_half(Bb, ldb, 1, smem + 49152, 1, wave);
    vmw<10>();          // 14 issued -> oldest 4 (0.A0,0.B0) landed
    bar_raw();

    for (int t = 0; t < T - 2; ++t)
        tile_iter<0>(t, acc, av, bvh, smem, Ab, lda, Bb, ldb, wave, wm, wn, r16, quad);
    tile_iter<1>(T - 2, acc, av, bvh, smem, Ab, lda, Bb, ldb, wave, wm, wn, r16, quad);
    tile_iter<2>(T - 1, acc, av, bvh, smem, Ab, lda, Bb, ldb, wave, wm, wn, r16, quad);

    // ---- epilogue: stage to LDS (row-XOR-swizzled), coalesced int4 stores
    constexpr int EB = OUT_BF16 ? 2 : 4;
    constexpr int EPASS = OUT_BF16 ? 1 : 2;   // f32 = 2 passes of 128 rows (ih=pass)
    char* Cb = reinterpret_cast<char*>((KS > 1 && z >= 2) ? Cv2 : Cv);
    if (KS > 1) Cb += (long)(z & 1) * czs * EB;
    float bsv[2][2];
    if (EPI == 1) {
        #pragma unroll
        for (int jh = 0; jh < 2; ++jh)
            #pragma unroll
            for (int j = 0; j < 2; ++j)
                bsv[jh][j] = bias[bn0 + jh * 128 + wn * 32 + j * 16 + r16];
    }
    u16* sm16 = smem;
    float* smf = reinterpret_cast<float*>(smem);
    #pragma unroll
    for (int pass = 0; pass < EPASS; ++pass) {
        bar_raw();
        #pragma unroll
        for (int ih = 0; ih < 2; ++ih) {
            if (EPASS == 2 && ih != pass) continue;
            #pragma unroll
            for (int ii = 0; ii < 4; ++ii)
                #pragma unroll
                for (int jh = 0; jh < 2; ++jh)
                    #pragma unroll
                    for (int j = 0; j < 2; ++j)
                        #pragma unroll
                        for (int r = 0; r < 4; ++r) {
                            int lrow = (EPASS == 2 ? 0 : ih * 128) + wm * 64 + ii * 16 + quad * 4 + r;
                            int lcol = jh * 128 + wn * 32 + j * 16 + r16;
                            float v = acc[ih][ii][jh][j][r] * alpha;
                            if (EPI == 1) { v += bsv[jh][j]; v = v > 0.f ? v : 0.f; }
                            int scol = lcol ^ ((lrow & 7) * 8);
                            if (OUT_BF16) sm16[lrow * 256 + scol] = f2bf(v);
                            else          smf[lrow * 256 + scol] = v;
                        }
        }
        bar_raw();
        constexpr int CH = 16 / EB;
        constexpr int CPR = 256 / CH;
        constexpr int NCH = (OUT_BF16 ? 256 : 128) * CPR / 512;
        #pragma unroll
        for (int c = 0; c < NCH; ++c) {
            int cid = tid + c * 512;
            int row = cid / CPR, ch = cid - row * CPR;
            int col = (ch * CH) ^ ((row & 7) * 8);
            int4 v = *reinterpret_cast<const int4*>(
                reinterpret_cast<const char*>(smem) + ((long)row * 256 + col) * EB);
            long grow = bm0 + pass * 128 + row;
            *reinterpret_cast<int4*>(Cb + (grow * ldc + bn0 + ch * CH) * EB) = v;
        }
    }
}

// ---------------- fused attention PV: recompute E per tile, x scaled V ----------------
// Grid 512 blocks: L -> xcd=L&7: head=(L&7)*2+((L>>3)&1), tb=(L>>4)&7, b=L>>7.
// Per block: out[128 t][64 v] = sum_s exp(0.125*Q K^T) * Vt_scaled.
__global__ __launch_bounds__(256) void attn_pv_k(
    const u16* __restrict__ Qg, long ldq, long qbz,
    const u16* __restrict__ Kg, long ldk, long kbz,
    const u16* __restrict__ Vg,            // [b][1024 hv][1024 s], pre-scaled by 1/l
    u16* __restrict__ outg)                // part: [b][1024 t][1024 (h*64+v)]
{
    __shared__ __align__(16) u16 Qs[128 * 64];
    __shared__ __align__(16) u16 Ks[64 * 64];
    __shared__ __align__(16) u16 Vs[64 * 64];
    __shared__ __align__(16) u16 Es[128 * 64];

    int L = blockIdx.x;
    int h  = (L & 7) * 2 + ((L >> 3) & 1);
    int tb = (L >> 4) & 7;
    int b  = L >> 7;

    const u16* Q  = Qg + (long)b * qbz + h * 64;
    const u16* Kp = Kg + (long)b * kbz + h * 64;
    const u16* Vp = Vg + (long)b * 1048576 + (long)h * 65536;
    u16* outp = outg + (long)b * 1048576 + (long)tb * 131072 + h * 64;

    int tid = threadIdx.x, lane = tid & 63, wave = tid >> 6;
    int wm = wave >> 1, wn = wave & 1;
    int r16 = lane & 15, quad = lane >> 4, l8 = lane >> 3;
    int gsw = ((lane & 7) ^ l8) * 8;
    long t0 = (long)tb * 128;

    #pragma unroll
    for (int s = wave; s < 16; s += 4)
        gl_lds16(&Q[(t0 + s * 8 + l8) * ldq + gsw], &Qs[s * 512]);

    f32x4 acc[4][2];
    #pragma unroll
    for (int i = 0; i < 4; ++i)
        #pragma unroll
        for (int j = 0; j < 2; ++j) {
            acc[i][j][0] = 0.f; acc[i][j][1] = 0.f;
            acc[i][j][2] = 0.f; acc[i][j][3] = 0.f;
        }

    for (int sc = 0; sc < 16; ++sc) {
        #pragma unroll
        for (int s = wave; s < 8; s += 4) {
            gl_lds16(&Kp[(long)(sc * 64 + s * 8 + l8) * ldk + gsw], &Ks[s * 512]);
            gl_lds16(&Vp[(long)(s * 8 + l8) * 1024 + sc * 64 + gsw], &Vs[s * 512]);
        }
        __syncthreads();                       // K/V (and Q on sc==0) staged

        // E-chunk = Q x K^T (128x64, contraction 64)
        f32x4 e[4][2];
        #pragma unroll
        for (int i = 0; i < 4; ++i)
            #pragma unroll
            for (int j = 0; j < 2; ++j) {
                e[i][j][0] = 0.f; e[i][j][1] = 0.f;
                e[i][j][2] = 0.f; e[i][j][3] = 0.f;
            }
        #pragma unroll
        for (int kk = 0; kk < 64; kk += 32) {
            int cb = (kk >> 3) + quad;
            bf16x8 av[4], bv[2];
            #pragma unroll
            for (int i = 0; i < 4; ++i) {
                int r = wm * 64 + i * 16 + r16;
                av[i] = *reinterpret_cast<const bf16x8*>(&Qs[r * 64 + ((cb ^ (r & 7)) * 8)]);
            }
            #pragma unroll
            for (int j = 0; j < 2; ++j) {
                int r = wn * 32 + j * 16 + r16;
                bv[j] = *reinterpret_cast<const bf16x8*>(&Ks[r * 64 + ((cb ^ (r & 7)) * 8)]);
            }
            #pragma unroll
            for (int i = 0; i < 4; ++i)
                #pragma unroll
                for (int j = 0; j < 2; ++j)
                    e[i][j] = __builtin_amdgcn_mfma_f32_16x16x32_bf16(av[i], bv[j], e[i][j], 0, 0, 0);
        }
        // exp + write to Es (C-frag: row=quad*4+r, col=r16; XOR-swizzled rows)
        #pragma unroll
        for (int i = 0; i < 4; ++i)
            #pragma unroll
            for (int j = 0; j < 2; ++j) {
                int lcol = wn * 32 + j * 16 + r16;
                #pragma unroll
                for (int r = 0; r < 4; ++r) {
                    int lrow = wm * 64 + i * 16 + quad * 4 + r;
                    float v = __expf(e[i][j][r] * 0.125f);
                    Es[lrow * 64 + (((lcol >> 3) ^ (lrow & 7)) * 8) + (lcol & 7)] = f2bf(v);
                }
            }
        __syncthreads();                       // Es ready

        // acc += E-chunk x Vs^T (contraction over s-chunk)
        #pragma unroll
        for (int kk = 0; kk < 64; kk += 32) {
            int cb = (kk >> 3) + quad;
            bf16x8 av[4], bv[2];
            #pragma unroll
            for (int i = 0; i < 4; ++i) {
                int r = wm * 64 + i * 16 + r16;
                av[i] = *reinterpret_cast<const bf16x8*>(&Es[r * 64 + ((cb ^ (r & 7)) * 8)]);
            }
            #pragma unroll
            for (int j = 0; j < 2; ++j) {
                int r = wn * 32 + j * 16 + r16;
                bv[j] = *reinterpret_cast<const bf16x8*>(&Vs[r * 64 + ((cb ^ (r & 7)) * 8)]);
            }
            #pragma unroll
            for (int i = 0; i < 4; ++i)
                #pragma unroll
                for (int j = 0; j < 2; ++j)
                    acc[i][j] = __builtin_amdgcn_mfma_f32_16x16x32_bf16(av[i], bv[j], acc[i][j], 0, 0, 0);
        }
        __syncthreads();                       // PV done; next stage may overwrite K/V
    }

    #pragma unroll
    for (int i = 0; i < 4; ++i)
        #pragma unroll
        for (int j = 0; j < 2; ++j) {
            int lcol = wn * 32 + j * 16 + r16;
            #pragma unroll
            for (int r = 0; r < 4; ++r) {
                int lrow = wm * 64 + i * 16 + quad * 4 + r;
                outp[(long)lrow * 1024 + lcol] = f2bf(acc[i][j][r]);
            }
        }
}

// ---------------- Vt *= 1/l over all 4 batches: csum [4][16][1024] ----------------
__global__ __launch_bounds__(256) void vscale_k(u16* __restrict__ Vt, const float* __restrict__ csum) {
    long idx = (long)blockIdx.x * 256 + threadIdx.x;   // grid 2048
    int slab = (int)(idx >> 17);
    int rem = (int)(idx & 131071);
    int hv = rem >> 7;
    int s8 = (rem & 127) * 8;
    const float* cs = csum + slab * 16384 + (hv >> 6) * 1024 + s8;
    u16* pv = Vt + (long)slab * 1048576 + (long)hv * 1024 + s8;
    ushort4 a = *reinterpret_cast<ushort4*>(pv);
    ushort4 b = *reinterpret_cast<ushort4*>(pv + 4);
    a.x = f2bf(bf2f(a.x) / cs[0]); a.y = f2bf(bf2f(a.y) / cs[1]);
    a.z = f2bf(bf2f(a.z) / cs[2]); a.w = f2bf(bf2f(a.w) / cs[3]);
    b.x = f2bf(bf2f(b.x) / cs[4]); b.y = f2bf(bf2f(b.y) / cs[5]);
    b.z = f2bf(bf2f(b.z) / cs[6]); b.w = f2bf(bf2f(b.w) / cs[7]);
    *reinterpret_cast<ushort4*>(pv) = a;
    *reinterpret_cast<ushort4*>(pv + 4) = b;
}

// ---------------- out = (sum of NP partial slabs + resid [+bias]) - mean - std ----------------
// Slabs 0,1 from parts; slabs 2,3 (NP=4) from parts2.
template<int NP, int BIAS>
__global__ __launch_bounds__(256) void addsn_k(const float* __restrict__ parts,
                                               const float* __restrict__ parts2,
                                               long pstride,
                                               const float* __restrict__ resid,
                                               const float* __restrict__ bias,
                                               float* __restrict__ out) {
    __shared__ float sm[8];
    long row = blockIdx.x;
    int tid = threadIdx.x;
    float4 x = reinterpret_cast<const float4*>(resid + row * 1024)[tid];
    #pragma unroll
    for (int p = 0; p < NP; ++p) {
        const float* src = (p < 2) ? (parts + p * pstride) : (parts2 + (p - 2) * pstride);
        float4 a = reinterpret_cast<const float4*>(src + row * 1024)[tid];
        x.x += a.x; x.y += a.y; x.z += a.z; x.w += a.w;
    }
    if (BIAS) {
        float4 bb = reinterpret_cast<const float4*>(bias)[tid];
        x.x += bb.x; x.y += bb.y; x.z += bb.z; x.w += bb.w;
    }
    float s = x.x + x.y + x.z + x.w;
    for (int o = 32; o > 0; o >>= 1) s += __shfl_down(s, o, 64);
    int lane = tid & 63, w = tid >> 6;
    if (lane == 0) sm[w] = s;
    __syncthreads();
    float mean = (sm[0] + sm[1] + sm[2] + sm[3]) * (1.f / 1024.f);
    float d0 = x.x - mean, d1 = x.y - mean, d2 = x.z - mean, d3 = x.w - mean;
    float q = d0 * d0 + d1 * d1 + d2 * d2 + d3 * d3;
    for (int o = 32; o > 0; o >>= 1) q += __shfl_down(q, o, 64);
    if (lane == 0) sm[w + 4] = q;
    __syncthreads();
    float sd = sqrtf((sm[4] + sm[5] + sm[6] + sm[7]) * (1.f / 1023.f));
    float4 ov;
    ov.x = d0 - sd; ov.y = d1 - sd; ov.z = d2 - sd; ov.w = d3 - sd;
    reinterpret_cast<float4*>(out + row * 1024)[tid] = ov;
}

// ---------------- launcher ----------------

extern "C" void kernel_launch(void* const* d_in, const int* in_sizes, int n_in,
                              void* d_out, int out_size, void* d_ws, size_t ws_size,
                              hipStream_t stream) {
    (void)in_sizes; (void)n_in; (void)out_size; (void)ws_size;
    const float* xf   = (const float*)d_in[0];
    const float* yf   = (const float*)d_in[1];
    const float* Wq1  = (const float*)d_in[2];
    const float* Wk1  = (const float*)d_in[3];
    const float* Wv1  = (const float*)d_in[4];
    const float* Wo1  = (const float*)d_in[5];
    const float* Wq2  = (const float*)d_in[6];
    const float* Wk2  = (const float*)d_in[7];
    const float* Wv2  = (const float*)d_in[8];
    const float* Wo2  = (const float*)d_in[9];
    const float* W_in = (const float*)d_in[10];
    const float* b_in = (const float*)d_in[11];
    const float* W_out= (const float*)d_in[12];
    const float* b_out= (const float*)d_in[13];

    // workspace layout (~192 MB)
    char* p = (char*)d_ws;
    auto alloc = [&](size_t bytes) { char* r = p; p += bytes; return r; };
    u16*   yb    = (u16*)alloc(8388608);    // y bf16 (4096x1024)
    u16*   xb    = (u16*)alloc(8388608);    // x bf16
    u16*   W1cat = (u16*)alloc(8388608);    // [Wq1|Wk1|Wv1|Wq2]^T-packed (4096 x 1024)
    u16*   Wkv2t = (u16*)alloc(4194304);    // [Wk2|Wv2] (2048 x 1024)
    u16*   Wo1t  = (u16*)alloc(2097152);
    u16*   Wo2t  = (u16*)alloc(2097152);
    u16*   Winb  = (u16*)alloc(8388608);    // W_in (4096 x 1024) = Bt layout
    u16*   Woutb = (u16*)alloc(8388608);    // W_out (1024 x 4096) = Bt layout
    u16*   QKV   = (u16*)alloc(33554432);   // (4096 x 4096): [Q1|K1|V1|Q2] per (b,t);
                                            // dead after MHA2 -> reused as FFN-out fp32 slabs 2,3
    u16*   KV2   = (u16*)alloc(16777216);   // (4096 x 2048): [K2|V2]
    u16*   Vt    = (u16*)alloc(8388608);    // per b: (1024 hv x 1024 s), scaled by 1/l in place
    u16*   Pb    = (u16*)alloc(33554432);   // FFN hidden (4096x4096 bf16)
    float* csum  = (float*)alloc(262144);   // column sums l [4][16][1024]
    u16*   part  = (u16*)alloc(8388608);    // attn partial (4096 x 1024) bf16
    float* gout  = (float*)alloc(33554432); // fp32 split-K partials, 2 slabs of 16 MB
    float* out1  = (float*)alloc(16777216);

    // ---- converts + weight packs ----
    convert_f2b_k<<<4096, 256, 0, stream>>>(yf, yb);
    convert_f2b_k<<<4096, 256, 0, stream>>>(xf, xb);
    pack_perm_t<<<dim3(1, 16, 16), 256, 0, stream>>>(Wq1, W1cat,           1024, 64);
    pack_perm_t<<<dim3(1, 16, 16), 256, 0, stream>>>(Wk1, W1cat + 1048576, 1024, 64);
    pack_perm_t<<<dim3(1, 16, 16), 256, 0, stream>>>(Wv1, W1cat + 2097152, 1024, 64);
    pack_perm_t<<<dim3(1, 16, 16), 256, 0, stream>>>(Wq2, W1cat + 3145728, 1024, 64);
    pack_perm_t<<<dim3(1, 16, 16), 256, 0, stream>>>(Wk2, Wkv2t,           1024, 64);
    pack_perm_t<<<dim3(1, 16, 16), 256, 0, stream>>>(Wv2, Wkv2t + 1048576, 1024, 64);
    pack_perm_t<<<dim3(16, 16, 1), 256, 0, stream>>>(Wo1, Wo1t,            1024, 1024);
    pack_perm_t<<<dim3(16, 16, 1), 256, 0, stream>>>(Wo2, Wo2t,            1024, 1024);
    convert_f2b_k<<<4096, 256, 0, stream>>>(W_in,  Winb);
    convert_f2b_k<<<4096, 256, 0, stream>>>(W_out, Woutb);

    // attention core: all 4 batches per dispatch.
    auto run_attention = [&](const u16* Q, long ldq, long qbz,
                             const u16* Kp, long ldk, long kbz,
                             const u16* Vp, long ldv, long vbz) {
        transpose_k<<<dim3(16, 16, 4), 256, 0, stream>>>(Vp, ldv, vbz, Vt, 1024L, 1048576L);
        hipMemsetAsync(csum, 0, 262144, stream);
        // l-pass: exp column-sums, no stores. z=(b,h): zi=h (stride 64), zo=b.
        gemm_k<128,128,64,2,2,1,4,0,1><<<dim3(8, 8, 64), 256, 0, stream>>>(
            Q, ldq, 64L, qbz, Kp, ldk, 64L, kbz,
            (void*)Pb, 1024L, 0L, 0L, 16, 64, 0.125f, nullptr, csum);
        vscale_k<<<2048, 256, 0, stream>>>(Vt, csum);
        attn_pv_k<<<512, 256, 0, stream>>>(Q, ldq, qbz, Kp, ldk, kbz, Vt, part);
    };

    // ---- fused projections (8-phase 256^2): QKV1 + Q2 from y (N=4096) ----
    gemm8_k<16,1,0,1><<<256, 512, 0, stream>>>(
        yb, 1024L, W1cat, 1024L, (void*)QKV, nullptr, 4096L, 1024, 1.0f, nullptr, 0L);
    // K2/V2 from x, N=2048
    gemm8_k<8,1,0,1><<<128, 512, 0, stream>>>(
        xb, 1024L, Wkv2t, 1024L, (void*)KV2, nullptr, 2048L, 1024, 1.0f, nullptr, 0L);

    // ---- MHA1 (self-attn on y): Q/K/V at cols 0/1024/2048 of QKV ----
    run_attention(QKV, 4096L, 4194304L, QKV + 1024, 4096L, 4194304L, QKV + 2048, 4096L, 4194304L);
    gemm_k<128,64,64,2,2,0,0,4,2><<<dim3(2 * 512), 256, 0, stream>>>(
        part, 1024L, 0L, 512L, Wo1t, 1024L, 0L, 512L,
        (void*)gout, 1024L, 0L, 4194304L, 1, 512, 1.0f, nullptr, nullptr);
    addsn_k<2,0><<<4096, 256, 0, stream>>>(gout, nullptr, 4194304L, yf, nullptr, out1);

    // ---- MHA2 (q from y at QKV col 3072; k/v from x in KV2) ----
    run_attention(QKV + 3072, 4096L, 4194304L, KV2, 2048L, 2097152L, KV2 + 1024, 2048L, 2097152L);
    gemm_k<128,64,64,2,2,0,0,4,2><<<dim3(2 * 512), 256, 0, stream>>>(
        part, 1024L, 0L, 512L, Wo2t, 1024L, 0L, 512L,
        (void*)gout, 1024L, 0L, 4194304L, 1, 512, 1.0f, nullptr, nullptr);
    addsn_k<2,0><<<4096, 256, 0, stream>>>(gout, nullptr, 4194304L, out1, nullptr, (float*)d_out);

    // ---- FFN on y (hidden in Pb: 4096x4096 bf16), 8-phase GEMMs ----
    gemm8_k<16,1,1,1><<<256, 512, 0, stream>>>(
        yb, 1024L, Winb, 1024L, (void*)Pb, nullptr, 4096L, 1024, 1.0f, b_in, 0L);
    // FFN-out: split-K 4 (full machine); slabs 0,1 -> gout, slabs 2,3 -> dead QKV region
    gemm8_k<4,4,0,0><<<256, 512, 0, stream>>>(
        Pb, 4096L, Woutb, 4096L, (void*)gout, (void*)QKV, 1024L, 1024, 1.0f, nullptr, 4194304L);
    addsn_k<4,1><<<4096, 256, 0, stream>>>(gout, (const float*)QKV, 4194304L,
                                           (const float*)d_out, b_out, (float*)d_out);
}